// Round 1
// baseline (4869.814 us; speedup 1.0000x reference)
//
#include <hip/hip_runtime.h>
#include <math.h>

// Problem constants (from reference)
static const int N0 = 1000000, N1 = 100000, N2 = 10000, N3 = 1024;
static const int E0 = 1500000, E1 = 150000, E2 = 15360;
static const int D = 128, H = 512;

// ---------------------------------------------------------------------------
// Edge-count: cnt[dst[e]] += 1
// ---------------------------------------------------------------------------
__global__ void count_kernel(const int* __restrict__ dst, float* __restrict__ cnt, int E) {
    int e = blockIdx.x * blockDim.x + threadIdx.x;
    if (e < E) atomicAdd(cnt + dst[e], 1.0f);
}

// ---------------------------------------------------------------------------
// Scatter-add: agg[dst[e]] += x[src[e]]   (thread = (edge, float4 chunk))
// ---------------------------------------------------------------------------
__global__ void scatter_kernel(const float* __restrict__ x,
                               const int* __restrict__ src,
                               const int* __restrict__ dst,
                               float* __restrict__ agg,
                               int E, int Din, int lognv) {
    long long gid = (long long)blockIdx.x * blockDim.x + threadIdx.x;
    int nv = Din >> 2;                       // float4 chunks per row
    int e = (int)(gid >> lognv);
    int v = (int)(gid & (nv - 1));
    if (e >= E) return;
    long long s = src[e];
    long long d = dst[e];
    float4 val = *(const float4*)(x + s * Din + v * 4);
    float* ad = agg + d * Din + v * 4;
    atomicAdd(ad + 0, val.x);
    atomicAdd(ad + 1, val.y);
    atomicAdd(ad + 2, val.z);
    atomicAdd(ad + 3, val.w);
}

// ---------------------------------------------------------------------------
// Fused combine: out = act( (agg/max(cnt,1)) @ Wl + b + xt @ Wr )
// 64x64 block tile, 256 threads, 4x4 micro-tile per thread, fp32.
// ---------------------------------------------------------------------------
template <bool GELU>
__global__ __launch_bounds__(256)
void combine_kernel(const float* __restrict__ agg, const float* __restrict__ cnt,
                    const float* __restrict__ xt,
                    const float* __restrict__ Wl, const float* __restrict__ Wr,
                    const float* __restrict__ bias,
                    float* __restrict__ out, int M, int K, int N) {
    __shared__ __align__(16) float As[16][68];   // [k][m], pad keeps 16B-aligned float4 reads
    __shared__ __align__(16) float Bs[16][64];   // [k][n]
    __shared__ float invs[64];

    int t = threadIdx.x;
    int m0 = blockIdx.y * 64;
    int n0 = blockIdx.x * 64;

    if (t < 64) {
        int r = m0 + t;
        float c = (r < M) ? cnt[r] : 1.0f;
        invs[t] = 1.0f / fmaxf(c, 1.0f);
    }

    int tx = t & 15, ty = t >> 4;       // 16x16 thread grid
    int lm = t >> 2;                    // A-load: row in tile (0..63)
    int lk = (t & 3) * 4;               // A-load: k in tile {0,4,8,12}
    int bk = t >> 4;                    // B-load: k in tile (0..15)
    int bn = (t & 15) * 4;              // B-load: n in tile {0..60}

    float acc[4][4] = {};
    __syncthreads();

    for (int p = 0; p < 2; ++p) {
        const float* A = p ? xt : agg;
        const float* B = p ? Wr : Wl;
        float sc_base = p ? 1.0f : invs[lm];
        for (int k0 = 0; k0 < K; k0 += 16) {
            // stage A tile (64 rows x 16 k), scaled by 1/cnt on pass 0
            int r = m0 + lm;
            float4 av = make_float4(0.f, 0.f, 0.f, 0.f);
            if (r < M) av = *(const float4*)(A + (long long)r * K + k0 + lk);
            As[lk + 0][lm] = av.x * sc_base;
            As[lk + 1][lm] = av.y * sc_base;
            As[lk + 2][lm] = av.z * sc_base;
            As[lk + 3][lm] = av.w * sc_base;
            // stage B tile (16 k x 64 n)
            *(float4*)&Bs[bk][bn] = *(const float4*)(B + (long long)(k0 + bk) * N + n0 + bn);
            __syncthreads();
#pragma unroll
            for (int kk = 0; kk < 16; ++kk) {
                float4 a4 = *(const float4*)&As[kk][ty * 4];
                float4 b4 = *(const float4*)&Bs[kk][tx * 4];
                float a[4] = {a4.x, a4.y, a4.z, a4.w};
                float b[4] = {b4.x, b4.y, b4.z, b4.w};
#pragma unroll
                for (int i = 0; i < 4; ++i)
#pragma unroll
                    for (int j = 0; j < 4; ++j) acc[i][j] += a[i] * b[j];
            }
            __syncthreads();
        }
    }

    // epilogue: bias + optional exact GELU
#pragma unroll
    for (int i = 0; i < 4; ++i) {
        int r = m0 + ty * 4 + i;
        if (r < M) {
#pragma unroll
            for (int j = 0; j < 4; ++j) {
                int c = n0 + tx * 4 + j;
                float v = acc[i][j] + bias[c];
                if (GELU) v = 0.5f * v * (1.0f + erff(v * 0.70710678118654752f));
                out[(long long)r * N + c] = v;
            }
        }
    }
}

// ---------------------------------------------------------------------------
extern "C" void kernel_launch(void* const* d_in, const int* in_sizes, int n_in,
                              void* d_out, int out_size, void* d_ws, size_t ws_size,
                              hipStream_t stream) {
    const float* x       = (const float*)d_in[0];
    const int*   ei0_src = (const int*)d_in[1];
    const int*   ei0_dst = (const int*)d_in[2];
    const int*   ei1_src = (const int*)d_in[3];
    const int*   ei1_dst = (const int*)d_in[4];
    const int*   ei2_src = (const int*)d_in[5];
    const int*   ei2_dst = (const int*)d_in[6];
    const float* W_l0    = (const float*)d_in[7];
    const float* b_l0    = (const float*)d_in[8];
    const float* W_r0    = (const float*)d_in[9];
    const float* W_l1    = (const float*)d_in[10];
    const float* b_l1    = (const float*)d_in[11];
    const float* W_r1    = (const float*)d_in[12];
    const float* W_l2    = (const float*)d_in[13];
    const float* b_l2    = (const float*)d_in[14];
    const float* W_r2    = (const float*)d_in[15];
    float* out = (float*)d_out;
    float* ws  = (float*)d_ws;

    // workspace layout (floats)
    float* h1   = ws;                              // N1*H = 51.2M
    float* agg0 = h1 + (size_t)N1 * H;             // N1*D = 12.8M
    float* cnt0 = agg0 + (size_t)N1 * D;           // N1
    // after layer-0 combine, reuse agg0 region:
    float* agg1 = agg0;                            // N2*H
    float* cnt1 = agg1 + (size_t)N2 * H;           // N2
    float* h2   = cnt1 + N2;                       // N2*H
    float* agg2 = h2 + (size_t)N2 * H;             // N3*H
    float* cnt2 = agg2 + (size_t)N3 * H;           // N3

    // ---------------- layer 0: x (N0,128) -> h1 (N1,512), GELU ----------------
    hipMemsetAsync(agg0, 0, ((size_t)N1 * D + N1) * sizeof(float), stream);
    count_kernel<<<(E0 + 255) / 256, 256, 0, stream>>>(ei0_dst, cnt0, E0);
    {
        long long tot = (long long)E0 * (D / 4);
        scatter_kernel<<<(int)((tot + 255) / 256), 256, 0, stream>>>(x, ei0_src, ei0_dst, agg0, E0, D, 5);
    }
    combine_kernel<true><<<dim3(H / 64, (N1 + 63) / 64), 256, 0, stream>>>(
        agg0, cnt0, x, W_l0, W_r0, b_l0, h1, N1, D, H);

    // ---------------- layer 1: h1 (N1,512) -> h2 (N2,512), GELU ----------------
    hipMemsetAsync(agg1, 0, ((size_t)N2 * H + N2) * sizeof(float), stream);
    count_kernel<<<(E1 + 255) / 256, 256, 0, stream>>>(ei1_dst, cnt1, E1);
    {
        long long tot = (long long)E1 * (H / 4);
        scatter_kernel<<<(int)((tot + 255) / 256), 256, 0, stream>>>(h1, ei1_src, ei1_dst, agg1, E1, H, 7);
    }
    combine_kernel<true><<<dim3(H / 64, (N2 + 63) / 64), 256, 0, stream>>>(
        agg1, cnt1, h1, W_l1, W_r1, b_l1, h2, N2, H, H);

    // ---------------- layer 2: h2 (N2,512) -> out (N3,128), no act ----------------
    hipMemsetAsync(agg2, 0, ((size_t)N3 * H + N3) * sizeof(float), stream);
    count_kernel<<<(E2 + 255) / 256, 256, 0, stream>>>(ei2_dst, cnt2, E2);
    {
        long long tot = (long long)E2 * (H / 4);
        scatter_kernel<<<(int)((tot + 255) / 256), 256, 0, stream>>>(h2, ei2_src, ei2_dst, agg2, E2, H, 7);
    }
    combine_kernel<false><<<dim3(D / 64, (N3 + 63) / 64), 256, 0, stream>>>(
        agg2, cnt2, h2, W_l2, W_r2, b_l2, out, N3, H, D);
}

// Round 2
// 1745.479 us; speedup vs baseline: 2.7900x; 2.7900x over previous
//
#include <hip/hip_runtime.h>
#include <math.h>

// Problem constants (from reference)
static const int N0 = 1000000, N1 = 100000, N2 = 10000, N3 = 1024;
static const int E0 = 1500000, E1 = 150000, E2 = 15360;
static const int D = 128, H = 512;

// ---------------------------------------------------------------------------
// Edge-count histogram: cnt[dst[e]] += 1 (int atomics, tiny)
// ---------------------------------------------------------------------------
__global__ void count_kernel(const int* __restrict__ dst, int* __restrict__ cnt, int E) {
    int e = blockIdx.x * blockDim.x + threadIdx.x;
    if (e < E) atomicAdd(cnt + dst[e], 1);
}

// ---------------------------------------------------------------------------
// Single-block exclusive scan: offs[i] = sum(cnt[0..i)), offs[N] = E
// ---------------------------------------------------------------------------
__global__ __launch_bounds__(1024)
void scan_kernel(const int* __restrict__ cnt, int* __restrict__ offs, int N, int E) {
    __shared__ int part[1024];
    int t = threadIdx.x;
    int per = (N + 1023) >> 10;
    int beg = t * per, end = min(beg + per, N);
    int s = 0;
    for (int i = beg; i < end; ++i) s += cnt[i];
    part[t] = s;
    __syncthreads();
    // Hillis-Steele inclusive scan over 1024 partials
    for (int off = 1; off < 1024; off <<= 1) {
        int v = (t >= off) ? part[t - off] : 0;
        __syncthreads();
        part[t] += v;
        __syncthreads();
    }
    int run = (t == 0) ? 0 : part[t - 1];
    for (int i = beg; i < end; ++i) { offs[i] = run; run += cnt[i]; }
    if (t == 0) offs[N] = E;
}

// ---------------------------------------------------------------------------
// Bucket fill: sorted[offs[dst[e]] + cursor++] = src[e]
// ---------------------------------------------------------------------------
__global__ void fill_kernel(const int* __restrict__ dst, const int* __restrict__ src,
                            const int* __restrict__ offs, int* __restrict__ cur,
                            int* __restrict__ sorted, int E) {
    int e = blockIdx.x * blockDim.x + threadIdx.x;
    if (e < E) {
        int d = dst[e];
        int p = offs[d] + atomicAdd(cur + d, 1);
        sorted[p] = src[e];
    }
}

// ---------------------------------------------------------------------------
// Gather-mean, D=128: one wave per dst node; lane holds float2 of the row.
// ---------------------------------------------------------------------------
__global__ __launch_bounds__(256)
void gather_mean_128(const float* __restrict__ x, const int* __restrict__ offs,
                     const int* __restrict__ srt, float* __restrict__ agg, int Ntgt) {
    int wid = (int)((blockIdx.x * 256 + threadIdx.x) >> 6);
    int lane = threadIdx.x & 63;
    if (wid >= Ntgt) return;
    int beg = offs[wid], end = offs[wid + 1];
    float ax = 0.f, ay = 0.f;
    int e = beg;
    for (; e + 4 <= end; e += 4) {
        int s0 = srt[e], s1 = srt[e + 1], s2 = srt[e + 2], s3 = srt[e + 3];
        float2 v0 = ((const float2*)(x + (size_t)s0 * 128))[lane];
        float2 v1 = ((const float2*)(x + (size_t)s1 * 128))[lane];
        float2 v2 = ((const float2*)(x + (size_t)s2 * 128))[lane];
        float2 v3 = ((const float2*)(x + (size_t)s3 * 128))[lane];
        ax += v0.x + v1.x + v2.x + v3.x;
        ay += v0.y + v1.y + v2.y + v3.y;
    }
    for (; e < end; ++e) {
        int s = srt[e];
        float2 v = ((const float2*)(x + (size_t)s * 128))[lane];
        ax += v.x; ay += v.y;
    }
    float inv = 1.0f / (float)max(end - beg, 1);
    ((float2*)(agg + (size_t)wid * 128))[lane] = make_float2(ax * inv, ay * inv);
}

// ---------------------------------------------------------------------------
// Gather-mean, D=512: one wave per (node, half); lane holds float4 of 256-float half.
// ---------------------------------------------------------------------------
__global__ __launch_bounds__(256)
void gather_mean_512(const float* __restrict__ x, const int* __restrict__ offs,
                     const int* __restrict__ srt, float* __restrict__ agg, int Ntgt) {
    int gw = (int)((blockIdx.x * 256 + threadIdx.x) >> 6);
    int lane = threadIdx.x & 63;
    int node = gw >> 1, half = gw & 1;
    if (node >= Ntgt) return;
    int beg = offs[node], end = offs[node + 1];
    int co = half * 256 + lane * 4;
    float4 acc = make_float4(0.f, 0.f, 0.f, 0.f);
    int e = beg;
    for (; e + 4 <= end; e += 4) {
        int s0 = srt[e], s1 = srt[e + 1], s2 = srt[e + 2], s3 = srt[e + 3];
        float4 v0 = *(const float4*)(x + (size_t)s0 * 512 + co);
        float4 v1 = *(const float4*)(x + (size_t)s1 * 512 + co);
        float4 v2 = *(const float4*)(x + (size_t)s2 * 512 + co);
        float4 v3 = *(const float4*)(x + (size_t)s3 * 512 + co);
        acc.x += v0.x + v1.x + v2.x + v3.x;
        acc.y += v0.y + v1.y + v2.y + v3.y;
        acc.z += v0.z + v1.z + v2.z + v3.z;
        acc.w += v0.w + v1.w + v2.w + v3.w;
    }
    for (; e < end; ++e) {
        int s = srt[e];
        float4 v = *(const float4*)(x + (size_t)s * 512 + co);
        acc.x += v.x; acc.y += v.y; acc.z += v.z; acc.w += v.w;
    }
    float inv = 1.0f / (float)max(end - beg, 1);
    acc.x *= inv; acc.y *= inv; acc.z *= inv; acc.w *= inv;
    *(float4*)(agg + (size_t)node * 512 + co) = acc;
}

// ---------------------------------------------------------------------------
// Fused combine: out = act( agg_mean @ Wl + b + xt @ Wr )
// 64x64 block tile, 256 threads, 4x4 micro-tile per thread, fp32.
// ---------------------------------------------------------------------------
template <bool GELU>
__global__ __launch_bounds__(256)
void combine_kernel(const float* __restrict__ agg,
                    const float* __restrict__ xt,
                    const float* __restrict__ Wl, const float* __restrict__ Wr,
                    const float* __restrict__ bias,
                    float* __restrict__ out, int M, int K, int N) {
    __shared__ __align__(16) float As[16][68];   // [k][m]
    __shared__ __align__(16) float Bs[16][64];   // [k][n]

    int t = threadIdx.x;
    int m0 = blockIdx.y * 64;
    int n0 = blockIdx.x * 64;

    int tx = t & 15, ty = t >> 4;       // 16x16 thread grid
    int lm = t >> 2;                    // A-load: row in tile (0..63)
    int lk = (t & 3) * 4;               // A-load: k in tile {0,4,8,12}
    int bk = t >> 4;                    // B-load: k in tile (0..15)
    int bn = (t & 15) * 4;              // B-load: n in tile {0..60}

    float acc[4][4] = {};

    for (int p = 0; p < 2; ++p) {
        const float* A = p ? xt : agg;
        const float* B = p ? Wr : Wl;
        for (int k0 = 0; k0 < K; k0 += 16) {
            int r = m0 + lm;
            float4 av = make_float4(0.f, 0.f, 0.f, 0.f);
            if (r < M) av = *(const float4*)(A + (size_t)r * K + k0 + lk);
            As[lk + 0][lm] = av.x;
            As[lk + 1][lm] = av.y;
            As[lk + 2][lm] = av.z;
            As[lk + 3][lm] = av.w;
            *(float4*)&Bs[bk][bn] = *(const float4*)(B + (size_t)(k0 + bk) * N + n0 + bn);
            __syncthreads();
#pragma unroll
            for (int kk = 0; kk < 16; ++kk) {
                float4 a4 = *(const float4*)&As[kk][ty * 4];
                float4 b4 = *(const float4*)&Bs[kk][tx * 4];
                float a[4] = {a4.x, a4.y, a4.z, a4.w};
                float b[4] = {b4.x, b4.y, b4.z, b4.w};
#pragma unroll
                for (int i = 0; i < 4; ++i)
#pragma unroll
                    for (int j = 0; j < 4; ++j) acc[i][j] += a[i] * b[j];
            }
            __syncthreads();
        }
    }

#pragma unroll
    for (int i = 0; i < 4; ++i) {
        int r = m0 + ty * 4 + i;
        if (r < M) {
#pragma unroll
            for (int j = 0; j < 4; ++j) {
                int c = n0 + tx * 4 + j;
                float v = acc[i][j] + bias[c];
                if (GELU) v = 0.5f * v * (1.0f + erff(v * 0.70710678118654752f));
                out[(size_t)r * N + c] = v;
            }
        }
    }
}

// ---------------------------------------------------------------------------
extern "C" void kernel_launch(void* const* d_in, const int* in_sizes, int n_in,
                              void* d_out, int out_size, void* d_ws, size_t ws_size,
                              hipStream_t stream) {
    const float* x       = (const float*)d_in[0];
    const int*   ei0_src = (const int*)d_in[1];
    const int*   ei0_dst = (const int*)d_in[2];
    const int*   ei1_src = (const int*)d_in[3];
    const int*   ei1_dst = (const int*)d_in[4];
    const int*   ei2_src = (const int*)d_in[5];
    const int*   ei2_dst = (const int*)d_in[6];
    const float* W_l0    = (const float*)d_in[7];
    const float* b_l0    = (const float*)d_in[8];
    const float* W_r0    = (const float*)d_in[9];
    const float* W_l1    = (const float*)d_in[10];
    const float* b_l1    = (const float*)d_in[11];
    const float* W_r1    = (const float*)d_in[12];
    const float* W_l2    = (const float*)d_in[13];
    const float* b_l2    = (const float*)d_in[14];
    const float* W_r2    = (const float*)d_in[15];
    float* out = (float*)d_out;
    float* ws  = (float*)d_ws;

    // ---- workspace layout (float slots) ----
    // h1 region (N1*H floats); its head is reused for layer-0 CSR ints
    // (dead before combine0 writes h1).
    float* h1 = ws;
    int* offs0 = (int*)ws;                 // N1+1
    int* cnt0  = offs0 + (N1 + 1);         // N1
    int* cur0  = cnt0 + N1;                // N1
    int* srt0  = cur0 + N1;                // E0       (total 1.8M ints << N1*H)

    float* agg0 = h1 + (size_t)N1 * H;     // N1*D floats; reused after combine0:
    float* agg1 = agg0;                    //   N2*H
    float* h2   = agg1 + (size_t)N2 * H;   //   N2*H
    float* agg2 = h2 + (size_t)N2 * H;     //   N3*H   (10.77M <= 12.8M)

    int* tail  = (int*)(agg0 + (size_t)N1 * D);
    int* offs1 = tail;                     // N2+1
    int* cnt1  = offs1 + (N2 + 1);         // N2
    int* cur1  = cnt1 + N2;                // N2
    int* srt1  = cur1 + N2;                // E1
    int* offs2 = srt1 + E1;                // N3+1
    int* cnt2  = offs2 + (N3 + 1);         // N3
    int* cur2  = cnt2 + N3;                // N3
    int* srt2  = cur2 + N3;                // E2

    // ---- build CSR buckets for all 3 layers (int-only work) ----
    hipMemsetAsync(cnt0, 0, 2 * N1 * sizeof(int), stream);   // cnt0+cur0
    hipMemsetAsync(cnt1, 0, 2 * N2 * sizeof(int), stream);   // cnt1+cur1
    hipMemsetAsync(cnt2, 0, 2 * N3 * sizeof(int), stream);   // cnt2+cur2
    count_kernel<<<(E0 + 255) / 256, 256, 0, stream>>>(ei0_dst, cnt0, E0);
    count_kernel<<<(E1 + 255) / 256, 256, 0, stream>>>(ei1_dst, cnt1, E1);
    count_kernel<<<(E2 + 255) / 256, 256, 0, stream>>>(ei2_dst, cnt2, E2);
    scan_kernel<<<1, 1024, 0, stream>>>(cnt0, offs0, N1, E0);
    scan_kernel<<<1, 1024, 0, stream>>>(cnt1, offs1, N2, E1);
    scan_kernel<<<1, 1024, 0, stream>>>(cnt2, offs2, N3, E2);
    fill_kernel<<<(E0 + 255) / 256, 256, 0, stream>>>(ei0_dst, ei0_src, offs0, cur0, srt0, E0);
    fill_kernel<<<(E1 + 255) / 256, 256, 0, stream>>>(ei1_dst, ei1_src, offs1, cur1, srt1, E1);
    fill_kernel<<<(E2 + 255) / 256, 256, 0, stream>>>(ei2_dst, ei2_src, offs2, cur2, srt2, E2);

    // ---- layer 0: x (N0,128) -> h1 (N1,512), GELU ----
    gather_mean_128<<<(N1 + 3) / 4, 256, 0, stream>>>(x, offs0, srt0, agg0, N1);
    combine_kernel<true><<<dim3(H / 64, (N1 + 63) / 64), 256, 0, stream>>>(
        agg0, x, W_l0, W_r0, b_l0, h1, N1, D, H);

    // ---- layer 1: h1 (N1,512) -> h2 (N2,512), GELU ----
    gather_mean_512<<<(2 * N2 + 3) / 4, 256, 0, stream>>>(h1, offs1, srt1, agg1, N2);
    combine_kernel<true><<<dim3(H / 64, (N2 + 63) / 64), 256, 0, stream>>>(
        agg1, h1, W_l1, W_r1, b_l1, h2, N2, H, H);

    // ---- layer 2: h2 (N2,512) -> out (N3,128), no act ----
    gather_mean_512<<<(2 * N3 + 3) / 4, 256, 0, stream>>>(h2, offs2, srt2, agg2, N3);
    combine_kernel<false><<<dim3(D / 64, (N3 + 63) / 64), 256, 0, stream>>>(
        agg2, h2, W_l2, W_r2, b_l2, out, N3, H, D);
}